// Round 6
// baseline (1031.842 us; speedup 1.0000x reference)
//
#include <hip/hip_runtime.h>
#include <math.h>

#define B_ 16
#define INC 512
#define OUTC 256
#define FD 1024
#define DK 128
#define T_ 14
#define HO 64
#define WO 64
#define SP (HO*WO)
#define KC5 32   // conv X slab channel stride (u16); linear 16B slots for global_load_lds

typedef unsigned short u16;
typedef __attribute__((ext_vector_type(8))) short shortx8;
typedef __attribute__((ext_vector_type(4))) float floatx4;

__device__ __forceinline__ float phi_f(float t) {
    return t > 0.0f ? t + 1.0f : expf(t);
}
__device__ __forceinline__ u16 f2bf(float f) {
    unsigned int u = __float_as_uint(f);
    unsigned int r = (u + 0x7fffu + ((u >> 16) & 1u)) >> 16;
    return (u16)r;
}
__device__ __forceinline__ float bf2f(u16 h) {
    return __uint_as_float(((unsigned int)h) << 16);
}

// ---------------- prep: xT[b][d][c] bf16 from x[b][c][d] fp32
__global__ __launch_bounds__(256) void kprep_x(const float* __restrict__ x, u16* __restrict__ xT) {
    __shared__ u16 T[64][65];
    int d0 = blockIdx.x * 64, c0 = blockIdx.y * 64, b = blockIdx.z;
    const float* src = x + (size_t)b * INC * FD;
    int tid = threadIdx.x, lr = tid >> 6, lc = tid & 63;
    #pragma unroll
    for (int i = 0; i < 16; ++i) {
        int c = lr + i * 4;
        T[lc][c] = f2bf(src[(size_t)(c0 + c) * FD + d0 + lc]);
    }
    __syncthreads();
    u16* dst = xT + (size_t)b * FD * INC;
    #pragma unroll
    for (int i = 0; i < 16; ++i) {
        int d = lr + i * 4;
        dst[(size_t)(d0 + d) * INC + c0 + lc] = T[d][lc];
    }
}

// ---------------- prep: generic transpose fp32[R][C] -> bf16[C][R]
__global__ __launch_bounds__(256) void ktr_w(const float* __restrict__ src, u16* __restrict__ dst,
                                             int R, int C) {
    __shared__ u16 T[64][65];
    int c0 = blockIdx.x * 64, r0 = blockIdx.y * 64;
    int tid = threadIdx.x, lr = tid >> 6, lc = tid & 63;
    #pragma unroll
    for (int i = 0; i < 16; ++i) {
        int r = lr + i * 4;
        T[lc][r] = f2bf(src[(size_t)(r0 + r) * C + c0 + lc]);
    }
    __syncthreads();
    #pragma unroll
    for (int i = 0; i < 16; ++i) {
        int c = lr + i * 4;
        dst[(size_t)(c0 + c) * R + r0 + lc] = T[c][lc];
    }
}

// ---------------- prep: conv weights to Wt[tap][o][c] bf16
__global__ void kw_tr(const float* __restrict__ c1_w, u16* __restrict__ Wt) {
    int i = blockIdx.x * 256 + threadIdx.x;
    if (i >= 256 * 512 * 9) return;
    int tap = i % 9; int t2 = i / 9;
    int c = t2 % 512; int o = t2 / 512;
    Wt[((size_t)tap * 256 + o) * 512 + c] = f2bf(c1_w[i]);
}

// ---------------- prep: zero only the border ring of padded P
__global__ __launch_bounds__(256) void kborder(u16* __restrict__ P) {
    int b = blockIdx.y;
    int cbase = blockIdx.x * 20;
    uint4 z = {0, 0, 0, 0};
    for (int i = threadIdx.x; i < 20 * 64; i += 256) {
        int c = cbase + (i >> 6);
        int sub = i & 63;
        int row, col;
        if (c < 66)       { row = 0;       col = c; }
        else if (c < 132) { row = 65;      col = c - 66; }
        else if (c < 196) { row = c - 131; col = 0; }
        else              { row = c - 195; col = 65; }
        *(uint4*)(P + ((size_t)(b * 66 + row) * 66 + col) * 512 + sub * 8) = z;
    }
}

// ---------------- K1: Q/KL/KR = phi(X @ W) via MFMA. M=512,N=128,K=1024.
__global__ __launch_bounds__(256) void k1_proj(const float* __restrict__ x,
        const u16* __restrict__ wqT, const u16* __restrict__ wklT, const u16* __restrict__ wkrT,
        u16* __restrict__ qb, u16* __restrict__ klt, u16* __restrict__ krt) {
    __shared__ u16 smem[8704];
    u16* As = smem;
    u16* Bs = smem + 5120;
    int z = blockIdx.z, t = z / 3, which = z - t * 3;
    int src = (which == 0) ? t + 1 : (which == 1 ? t : t + 2);
    const float* Af = x + (size_t)src * INC * FD;
    const u16* Bw = (which == 0) ? wqT : (which == 1 ? wklT : wkrT);
    int n0 = blockIdx.x * 64, m0 = blockIdx.y * 128;
    int tid = threadIdx.x, w = tid >> 6, lane = tid & 63, l15 = lane & 15, quad = lane >> 4;
    int sm = tid >> 2, sq = (tid & 3) * 8;
    floatx4 acc[2][4];
    #pragma unroll
    for (int i = 0; i < 2; ++i)
        #pragma unroll
        for (int j = 0; j < 4; ++j) acc[i][j] = (floatx4){0.f,0.f,0.f,0.f};

    for (int k0 = 0; k0 < FD; k0 += 32) {
        float4 v0 = *(const float4*)&Af[(size_t)(m0 + sm) * FD + k0 + sq];
        float4 v1 = *(const float4*)&Af[(size_t)(m0 + sm) * FD + k0 + sq + 4];
        float4 v2 = *(const float4*)&Af[(size_t)(m0 + 64 + sm) * FD + k0 + sq];
        float4 v3 = *(const float4*)&Af[(size_t)(m0 + 64 + sm) * FD + k0 + sq + 4];
        union { u16 h[8]; uint4 v; } p0, p1;
        p0.h[0]=f2bf(v0.x); p0.h[1]=f2bf(v0.y); p0.h[2]=f2bf(v0.z); p0.h[3]=f2bf(v0.w);
        p0.h[4]=f2bf(v1.x); p0.h[5]=f2bf(v1.y); p0.h[6]=f2bf(v1.z); p0.h[7]=f2bf(v1.w);
        p1.h[0]=f2bf(v2.x); p1.h[1]=f2bf(v2.y); p1.h[2]=f2bf(v2.z); p1.h[3]=f2bf(v2.w);
        p1.h[4]=f2bf(v3.x); p1.h[5]=f2bf(v3.y); p1.h[6]=f2bf(v3.z); p1.h[7]=f2bf(v3.w);
        *(uint4*)&As[sm * 40 + sq] = p0.v;
        *(uint4*)&As[(64 + sm) * 40 + sq] = p1.v;
        *(uint4*)&Bs[sm * 40 + sq] = *(const uint4*)&Bw[(size_t)(n0 + sm) * FD + k0 + sq];
        __syncthreads();
        shortx8 bfr[4];
        #pragma unroll
        for (int nt = 0; nt < 4; ++nt)
            bfr[nt] = *(const shortx8*)&Bs[(nt * 16 + l15) * 40 + quad * 8];
        #pragma unroll
        for (int mt = 0; mt < 2; ++mt) {
            shortx8 af = *(const shortx8*)&As[(w * 32 + mt * 16 + l15) * 40 + quad * 8];
            #pragma unroll
            for (int nt = 0; nt < 4; ++nt)
                acc[mt][nt] = __builtin_amdgcn_mfma_f32_16x16x32_bf16(af, bfr[nt], acc[mt][nt], 0, 0, 0);
        }
        __syncthreads();
    }
    if (which == 0) {
        u16* outp = qb + (size_t)t * INC * DK;
        #pragma unroll
        for (int mt = 0; mt < 2; ++mt)
            #pragma unroll
            for (int nt = 0; nt < 4; ++nt)
                #pragma unroll
                for (int r = 0; r < 4; ++r) {
                    int m_out = m0 + w * 32 + mt * 16 + quad * 4 + r;
                    int n_out = n0 + nt * 16 + l15;
                    outp[(size_t)m_out * DK + n_out] = f2bf(phi_f(acc[mt][nt][r]));
                }
    } else {
        u16* outp = ((which == 1) ? klt : krt) + (size_t)t * DK * INC;
        #pragma unroll
        for (int mt = 0; mt < 2; ++mt)
            #pragma unroll
            for (int nt = 0; nt < 4; ++nt)
                #pragma unroll
                for (int r = 0; r < 4; ++r) {
                    int mloc = w * 32 + mt * 16 + quad * 4 + r;
                    int nloc = nt * 16 + l15;
                    smem[nloc * 136 + mloc] = f2bf(phi_f(acc[mt][nt][r]));
                }
        __syncthreads();
        int dkl = tid >> 2, seg = tid & 3;
        const uint4* sp = (const uint4*)&smem[dkl * 136 + seg * 32];
        uint4* dp = (uint4*)&outp[(size_t)(n0 + dkl) * INC + m0 + seg * 32];
        dp[0] = sp[0]; dp[1] = sp[1]; dp[2] = sp[2]; dp[3] = sp[3];
    }
}

// ---------------- K2b: ksum[dk] += sum_n KL[n][dk]; parallel over n-blocks, vectorized
__global__ __launch_bounds__(128) void k2b_ksum(const u16* __restrict__ klt, const u16* __restrict__ krt,
                         float* __restrict__ ksuml, float* __restrict__ ksumr) {
    int t = blockIdx.x, nb = blockIdx.y;
    int dk = threadIdx.x;
    const u16* pl = klt + ((size_t)t * DK + dk) * INC + nb * 64;
    const u16* pr = krt + ((size_t)t * DK + dk) * INC + nb * 64;
    float s1 = 0.f, s2 = 0.f;
    #pragma unroll
    for (int i = 0; i < 8; ++i) {
        union { uint4 v; u16 h[8]; } a, b;
        a.v = *(const uint4*)(pl + i * 8);
        b.v = *(const uint4*)(pr + i * 8);
        #pragma unroll
        for (int e = 0; e < 8; ++e) { s1 += bf2f(a.h[e]); s2 += bf2f(b.h[e]); }
    }
    atomicAdd(&ksuml[t * DK + dk], s1);
    atomicAdd(&ksumr[t * DK + dk], s2);
}

// ---------------- K2c: z[n] = q[n,:].ksum + 1e-6 (vectorized q reads)
__global__ __launch_bounds__(512) void k2c_z(const u16* __restrict__ qb, const float* __restrict__ ksuml,
                      const float* __restrict__ ksumr, float* __restrict__ zl, float* __restrict__ zr) {
    int t = blockIdx.x; int n = threadIdx.x;
    const uint4* qp = (const uint4*)(qb + ((size_t)t * INC + n) * DK);
    const float* sl = ksuml + t * DK;
    const float* sr = ksumr + t * DK;
    float a = 0.f, b = 0.f;
    #pragma unroll
    for (int k16 = 0; k16 < 16; ++k16) {
        union { uint4 v; u16 h[8]; } q;
        q.v = qp[k16];
        #pragma unroll
        for (int e = 0; e < 8; ++e) {
            float qv = bf2f(q.h[e]);
            a = fmaf(qv, sl[k16 * 8 + e], a);
            b = fmaf(qv, sr[k16 * 8 + e], b);
        }
    }
    zl[t * INC + n] = a + 1e-6f;
    zr[t * INC + n] = b + 1e-6f;
}

// ---------------- K2: KVt[d][dk] = xT @ KLt-frag. M=1024,N=128,K=512.
__global__ __launch_bounds__(256) void k2_kv(const u16* __restrict__ xT,
        const u16* __restrict__ klt, const u16* __restrict__ krt,
        u16* __restrict__ kvlT, u16* __restrict__ kvrT) {
    __shared__ u16 As[128 * 40];
    __shared__ u16 Bs[64 * 40];
    int z = blockIdx.z, t = z >> 1, side = z & 1;
    const u16* A = xT + (size_t)(side ? t + 2 : t) * FD * INC;
    const u16* Bw = (side ? krt : klt) + (size_t)t * DK * INC;
    u16* outp = (side ? kvrT : kvlT) + (size_t)t * FD * DK;
    int n0 = blockIdx.x * 64, m0 = blockIdx.y * 128;
    int tid = threadIdx.x, w = tid >> 6, lane = tid & 63, l15 = lane & 15, quad = lane >> 4;
    int sm = tid >> 2, sq = (tid & 3) * 8;
    floatx4 acc[2][4];
    #pragma unroll
    for (int i = 0; i < 2; ++i)
        #pragma unroll
        for (int j = 0; j < 4; ++j) acc[i][j] = (floatx4){0.f,0.f,0.f,0.f};
    for (int k0 = 0; k0 < INC; k0 += 32) {
        *(uint4*)&As[sm * 40 + sq] = *(const uint4*)&A[(size_t)(m0 + sm) * INC + k0 + sq];
        *(uint4*)&As[(64 + sm) * 40 + sq] = *(const uint4*)&A[(size_t)(m0 + 64 + sm) * INC + k0 + sq];
        *(uint4*)&Bs[sm * 40 + sq] = *(const uint4*)&Bw[(size_t)(n0 + sm) * INC + k0 + sq];
        __syncthreads();
        shortx8 bfr[4];
        #pragma unroll
        for (int nt = 0; nt < 4; ++nt)
            bfr[nt] = *(const shortx8*)&Bs[(nt * 16 + l15) * 40 + quad * 8];
        #pragma unroll
        for (int mt = 0; mt < 2; ++mt) {
            shortx8 af = *(const shortx8*)&As[(w * 32 + mt * 16 + l15) * 40 + quad * 8];
            #pragma unroll
            for (int nt = 0; nt < 4; ++nt)
                acc[mt][nt] = __builtin_amdgcn_mfma_f32_16x16x32_bf16(af, bfr[nt], acc[mt][nt], 0, 0, 0);
        }
        __syncthreads();
    }
    #pragma unroll
    for (int mt = 0; mt < 2; ++mt)
        #pragma unroll
        for (int nt = 0; nt < 4; ++nt)
            #pragma unroll
            for (int r = 0; r < 4; ++r) {
                int m_out = m0 + w * 32 + mt * 16 + quad * 4 + r;
                int n_out = n0 + nt * 16 + l15;
                outp[(size_t)m_out * DK + n_out] = f2bf(acc[mt][nt][r]);
            }
}

// ---------------- K3: newT[d][n] = KVtL@Q^T/zl + KVtR@Q^T/zr + xT. M=1024,N=512,K=128.
__global__ __launch_bounds__(256) void k3_out(const u16* __restrict__ xT,
        const u16* __restrict__ qb, const u16* __restrict__ kvlT, const u16* __restrict__ kvrT,
        const float* __restrict__ zl, const float* __restrict__ zr, u16* __restrict__ newT) {
    __shared__ u16 As1[128 * 40];
    __shared__ u16 As2[128 * 40];
    __shared__ u16 Bs[64 * 40];
    int t = blockIdx.z;
    const u16* A1 = kvlT + (size_t)t * FD * DK;
    const u16* A2 = kvrT + (size_t)t * FD * DK;
    const u16* Bq = qb + (size_t)t * INC * DK;
    int n0 = blockIdx.x * 64, m0 = blockIdx.y * 128;
    int tid = threadIdx.x, w = tid >> 6, lane = tid & 63, l15 = lane & 15, quad = lane >> 4;
    int sm = tid >> 2, sq = (tid & 3) * 8;
    floatx4 accl[2][4], accr[2][4];
    #pragma unroll
    for (int i = 0; i < 2; ++i)
        #pragma unroll
        for (int j = 0; j < 4; ++j) {
            accl[i][j] = (floatx4){0.f,0.f,0.f,0.f};
            accr[i][j] = (floatx4){0.f,0.f,0.f,0.f};
        }
    for (int k0 = 0; k0 < DK; k0 += 32) {
        *(uint4*)&As1[sm * 40 + sq] = *(const uint4*)&A1[(size_t)(m0 + sm) * DK + k0 + sq];
        *(uint4*)&As1[(64 + sm) * 40 + sq] = *(const uint4*)&A1[(size_t)(m0 + 64 + sm) * DK + k0 + sq];
        *(uint4*)&As2[sm * 40 + sq] = *(const uint4*)&A2[(size_t)(m0 + sm) * DK + k0 + sq];
        *(uint4*)&As2[(64 + sm) * 40 + sq] = *(const uint4*)&A2[(size_t)(m0 + 64 + sm) * DK + k0 + sq];
        *(uint4*)&Bs[sm * 40 + sq] = *(const uint4*)&Bq[(size_t)(n0 + sm) * DK + k0 + sq];
        __syncthreads();
        shortx8 bfr[4];
        #pragma unroll
        for (int nt = 0; nt < 4; ++nt)
            bfr[nt] = *(const shortx8*)&Bs[(nt * 16 + l15) * 40 + quad * 8];
        #pragma unroll
        for (int mt = 0; mt < 2; ++mt) {
            shortx8 afl = *(const shortx8*)&As1[(w * 32 + mt * 16 + l15) * 40 + quad * 8];
            shortx8 afr = *(const shortx8*)&As2[(w * 32 + mt * 16 + l15) * 40 + quad * 8];
            #pragma unroll
            for (int nt = 0; nt < 4; ++nt) {
                accl[mt][nt] = __builtin_amdgcn_mfma_f32_16x16x32_bf16(afl, bfr[nt], accl[mt][nt], 0, 0, 0);
                accr[mt][nt] = __builtin_amdgcn_mfma_f32_16x16x32_bf16(afr, bfr[nt], accr[mt][nt], 0, 0, 0);
            }
        }
        __syncthreads();
    }
    float il[4], ir[4];
    #pragma unroll
    for (int nt = 0; nt < 4; ++nt) {
        int n_out = n0 + nt * 16 + l15;
        il[nt] = 1.0f / zl[t * INC + n_out];
        ir[nt] = 1.0f / zr[t * INC + n_out];
    }
    const u16* xc = xT + (size_t)(t + 1) * FD * INC;
    u16* outp = newT + (size_t)t * FD * INC;
    #pragma unroll
    for (int mt = 0; mt < 2; ++mt)
        #pragma unroll
        for (int nt = 0; nt < 4; ++nt)
            #pragma unroll
            for (int r = 0; r < 4; ++r) {
                int m_out = m0 + w * 32 + mt * 16 + quad * 4 + r;
                int n_out = n0 + nt * 16 + l15;
                float xv = bf2f(xc[(size_t)m_out * INC + n_out]);
                float v = xv + accl[mt][nt][r] * il[nt] + accr[mt][nt][r] * ir[nt];
                outp[(size_t)m_out * INC + n_out] = f2bf(v);
            }
}

// ---------------- K4: upT[px][m] = newT @ upwT; gate fused via LDS-transposed epilogue.
__global__ __launch_bounds__(256) void k4_up(const u16* __restrict__ xT,
        const u16* __restrict__ newT, const u16* __restrict__ upwT,
        const float* __restrict__ up_b, u16* __restrict__ P) {
    __shared__ u16 smem[12288];
    u16* As = smem;
    u16* Bs = smem + 5120;
    int b = blockIdx.z;
    const u16* A = (b == 0) ? xT
                 : (b == B_ - 1) ? (xT + (size_t)(B_ - 1) * FD * INC)
                 : (newT + (size_t)(b - 1) * FD * INC);
    int n0 = blockIdx.x * 64, m0 = blockIdx.y * 128;
    int tid = threadIdx.x, w = tid >> 6, lane = tid & 63, l15 = lane & 15, quad = lane >> 4;
    int sm = tid >> 2, sq = (tid & 3) * 8;
    floatx4 acc[2][4];
    #pragma unroll
    for (int i = 0; i < 2; ++i)
        #pragma unroll
        for (int j = 0; j < 4; ++j) acc[i][j] = (floatx4){0.f,0.f,0.f,0.f};
    for (int k0 = 0; k0 < INC; k0 += 32) {
        *(uint4*)&As[sm * 40 + sq] = *(const uint4*)&A[(size_t)(m0 + sm) * INC + k0 + sq];
        *(uint4*)&As[(64 + sm) * 40 + sq] = *(const uint4*)&A[(size_t)(m0 + 64 + sm) * INC + k0 + sq];
        *(uint4*)&Bs[sm * 40 + sq] = *(const uint4*)&upwT[(size_t)(n0 + sm) * INC + k0 + sq];
        __syncthreads();
        shortx8 bfr[4];
        #pragma unroll
        for (int nt = 0; nt < 4; ++nt)
            bfr[nt] = *(const shortx8*)&Bs[(nt * 16 + l15) * 40 + quad * 8];
        #pragma unroll
        for (int mt = 0; mt < 2; ++mt) {
            shortx8 af = *(const shortx8*)&As[(w * 32 + mt * 16 + l15) * 40 + quad * 8];
            #pragma unroll
            for (int nt = 0; nt < 4; ++nt)
                acc[mt][nt] = __builtin_amdgcn_mfma_f32_16x16x32_bf16(af, bfr[nt], acc[mt][nt], 0, 0, 0);
        }
        __syncthreads();
    }
    u16* Ts = smem;
    int ppos = (l15 & 3) * 128;
    #pragma unroll
    for (int mt = 0; mt < 2; ++mt)
        #pragma unroll
        for (int nt = 0; nt < 4; ++nt) {
            int lm = nt * 16 + l15;
            float bias = up_b[(n0 + lm) >> 2];
            int o_rel = lm >> 2;
            #pragma unroll
            for (int r = 0; r < 4; ++r) {
                int l = w * 32 + mt * 16 + quad * 4 + r;
                Ts[(ppos + l) * 24 + o_rel] = f2bf(acc[mt][nt][r] + bias);
            }
        }
    __syncthreads();
    #pragma unroll
    for (int j2 = 0; j2 < 2; ++j2) {
        int pi = tid + j2 * 256;
        int pp = pi >> 7, l = pi & 127;
        int aa = pp >> 1, cbb = pp & 1;
        int px = m0 + l;
        int row = 2 * (px >> 5) + aa, colq = 2 * (px & 31) + cbb;
        size_t dst = ((size_t)(b * 66 + 1 + row) * 66 + 1 + colq) * 512 + (n0 >> 2);
        union { uint4 v; u16 h[8]; } a0, a1, s0, s1, g0, g1;
        a0.v = *(const uint4*)&Ts[pi * 24];
        a1.v = *(const uint4*)&Ts[pi * 24 + 8];
        s0.v = *(const uint4*)(P + dst + 256);
        s1.v = *(const uint4*)(P + dst + 256 + 8);
        #pragma unroll
        for (int e = 0; e < 8; ++e) {
            float r0 = fmaxf(bf2f(a0.h[e]) + bf2f(s0.h[e]), 0.0f);
            float r1 = fmaxf(bf2f(a1.h[e]) + bf2f(s1.h[e]), 0.0f);
            g0.h[e] = f2bf(1.0f / (1.0f + expf(-r0)));
            g1.h[e] = f2bf(1.0f / (1.0f + expf(-r1)));
        }
        *(uint4*)(P + dst) = g0.v;
        *(uint4*)(P + dst + 8) = g1.v;
    }
}

// ---------------- K4b: skip s -> bf16 into padded P (channels 256..511)
__global__ __launch_bounds__(256) void k4b_sfill(const float* __restrict__ s_in,
                                                 u16* __restrict__ P) {
    __shared__ u16 T[64 * 264];
    int p = blockIdx.x;
    int b = blockIdx.y;
    int tid = threadIdx.x;
    int qcol = tid & 63;
    int ob = tid >> 6;
    for (int o = ob; o < 256; o += 4) {
        float v = s_in[((size_t)(b * OUTC + o) * HO + p) * WO + qcol];
        T[qcol * 264 + o] = f2bf(v);
    }
    __syncthreads();
    int q2 = tid >> 2;
    int sg = tid & 3;
    size_t base = ((size_t)(b * 66 + 1 + p) * 66 + 1 + q2) * 512 + 256;
    #pragma unroll
    for (int it = 0; it < 8; ++it) {
        int seg = sg + it * 4;
        uint4 v = *(const uint4*)&T[q2 * 264 + seg * 8];
        *(uint4*)(P + base + seg * 8) = v;
    }
}

// ---------------- K5: conv3x3 MFMA implicit GEMM.
// Double-buffered X slab (global_load_lds), o-tile 128/wave (nt=8),
// weight frags double-buffered across taps (parity (ch+tap)&1), fused BN partial sums.
__global__ __launch_bounds__(256, 2) void k5_mfma(const u16* __restrict__ P,
        const u16* __restrict__ Wt, const float* __restrict__ c1_b,
        float* __restrict__ y, float* __restrict__ bnsum, float* __restrict__ bnsq) {
    __shared__ u16 Xs[2][6 * 66 * KC5];   // 2 x 25344 B
    int rb = blockIdx.x;          // 16 row-blocks (4 output rows each)
    int o0 = blockIdx.y * 128;    // 2 o-blocks of 128
    int b  = blockIdx.z;
    int tid = threadIdx.x;
    int w = tid >> 6, lane = tid & 63;
    int l15 = lane & 15, quad = lane >> 4;

    floatx4 acc[4][8];
    #pragma unroll
    for (int i = 0; i < 4; ++i)
        #pragma unroll
        for (int j = 0; j < 8; ++j)
            acc[i][j] = (floatx4){0.f, 0.f, 0.f, 0.f};

    size_t Pbase = ((size_t)b * 66 + (size_t)rb * 4) * 66 * 512;   // 396 contiguous pixels
    const u16* Wbase = Wt + ((size_t)(o0 + l15)) * 512 + quad * 8;

    // stage chunk 0 -> buf 0
    #pragma unroll
    for (int it = 0; it < 7; ++it) {
        int s = it * 256 + tid;
        if (s < 1584) {
            int pix = s >> 2, cs = s & 3;
            const u16* gp = P + Pbase + (size_t)pix * 512 + cs * 8;
            __builtin_amdgcn_global_load_lds(
                (const __attribute__((address_space(1))) void*)gp,
                (__attribute__((address_space(3))) void*)&Xs[0][(size_t)(it * 256 + w * 64) * 8],
                16, 0, 0);
        }
    }
    shortx8 wfb[2][8];
    #pragma unroll
    for (int nt = 0; nt < 8; ++nt)
        wfb[0][nt] = *(const shortx8*)(Wbase + ((size_t)nt * 16) * 512);

    for (int ch = 0; ch < 16; ++ch) {
        int c0 = ch * 32;
        __syncthreads();   // drains stage(ch) (compiler vmcnt(0)) + ends prior compute
        if (ch < 15) {
            int c1 = c0 + 32;
            int nb = (ch + 1) & 1;
            #pragma unroll
            for (int it = 0; it < 7; ++it) {
                int s = it * 256 + tid;
                if (s < 1584) {
                    int pix = s >> 2, cs = s & 3;
                    const u16* gp = P + Pbase + (size_t)pix * 512 + c1 + cs * 8;
                    __builtin_amdgcn_global_load_lds(
                        (const __attribute__((address_space(1))) void*)gp,
                        (__attribute__((address_space(3))) void*)&Xs[nb][(size_t)(it * 256 + w * 64) * 8],
                        16, 0, 0);
                }
            }
        }
        const u16* xb = Xs[ch & 1];
        #pragma unroll
        for (int tap = 0; tap < 9; ++tap) {
            int wsel = (ch + tap) & 1;
            if (tap < 8) {
                #pragma unroll
                for (int nt = 0; nt < 8; ++nt)
                    wfb[wsel ^ 1][nt] = *(const shortx8*)(Wbase +
                        ((size_t)((tap + 1) * 256 + nt * 16)) * 512 + c0);
            } else if (ch < 15) {
                #pragma unroll
                for (int nt = 0; nt < 8; ++nt)
                    wfb[wsel ^ 1][nt] = *(const shortx8*)(Wbase +
                        ((size_t)(nt * 16)) * 512 + c0 + 32);
            }
            int dy = tap / 3, dx = tap - dy * 3;
            #pragma unroll
            for (int mt = 0; mt < 4; ++mt) {
                shortx8 af = *(const shortx8*)&xb[((w + dy) * 66 + mt * 16 + l15 + dx) * KC5 + quad * 8];
                #pragma unroll
                for (int nt = 0; nt < 8; ++nt)
                    acc[mt][nt] = __builtin_amdgcn_mfma_f32_16x16x32_bf16(
                        af, wfb[wsel][nt], acc[mt][nt], 0, 0, 0);
            }
        }
    }
    // epilogue: bias + y store + fused BN partial sums
    int row = rb * 4 + w;
    #pragma unroll
    for (int nt = 0; nt < 8; ++nt) {
        int o = o0 + nt * 16 + l15;
        float bias = c1_b[o];
        float s1 = 0.f, s2 = 0.f;
        size_t ybase = (size_t)(b * OUTC + o) * SP + row * 64;
        #pragma unroll
        for (int mt = 0; mt < 4; ++mt) {
            float4 v;
            v.x = acc[mt][nt][0] + bias;
            v.y = acc[mt][nt][1] + bias;
            v.z = acc[mt][nt][2] + bias;
            v.w = acc[mt][nt][3] + bias;
            *(float4*)&y[ybase + mt * 16 + quad * 4] = v;
            s1 += v.x + v.y + v.z + v.w;
            s2 += v.x * v.x + v.y * v.y + v.z * v.z + v.w * v.w;
        }
        s1 += __shfl_xor(s1, 16);
        s1 += __shfl_xor(s1, 32);
        s2 += __shfl_xor(s2, 16);
        s2 += __shfl_xor(s2, 32);
        if (quad == 0) {
            atomicAdd(&bnsum[o], s1);
            atomicAdd(&bnsq[o], s2);
        }
    }
}

// ---------------- K7: BN finalize
__global__ void k7_bnfin(const float* __restrict__ bnsum, const float* __restrict__ bnsq,
                         const float* __restrict__ bn_g, const float* __restrict__ bn_b,
                         float* __restrict__ scale, float* __restrict__ shift) {
    int o = threadIdx.x;
    float cnt = (float)(B_ * SP);
    float mu = bnsum[o] / cnt;
    float var = bnsq[o] / cnt - mu * mu;
    float sc = bn_g[o] * rsqrtf(var + 1e-5f);
    scale[o] = sc;
    shift[o] = bn_b[o] - mu * sc;
}

// ---------------- K8: BN apply + relu
__global__ __launch_bounds__(256) void k8_apply(float* __restrict__ y,
        const float* __restrict__ scale, const float* __restrict__ shift) {
    int i = blockIdx.x * 256 + threadIdx.x;
    int o = (i >> 10) & 255;
    float4 v = ((float4*)y)[i];
    float sc = scale[o], sh = shift[o];
    v.x = fmaxf(fmaf(v.x, sc, sh), 0.f);
    v.y = fmaxf(fmaf(v.y, sc, sh), 0.f);
    v.z = fmaxf(fmaf(v.z, sc, sh), 0.f);
    v.w = fmaxf(fmaf(v.w, sc, sh), 0.f);
    ((float4*)y)[i] = v;
}

extern "C" void kernel_launch(void* const* d_in, const int* in_sizes, int n_in,
                              void* d_out, int out_size, void* d_ws, size_t ws_size,
                              hipStream_t stream) {
    const float* x    = (const float*)d_in[0];
    const float* s_in = (const float*)d_in[1];
    const float* up_w = (const float*)d_in[2];
    const float* up_b = (const float*)d_in[3];
    const float* wq   = (const float*)d_in[4];
    const float* wkl  = (const float*)d_in[5];
    const float* wkr  = (const float*)d_in[6];
    const float* c1_w = (const float*)d_in[7];
    const float* c1_b = (const float*)d_in[8];
    const float* bn_g = (const float*)d_in[9];
    const float* bn_b = (const float*)d_in[10];
    float* y = (float*)d_out;
    float* ws = (float*)d_ws;

    size_t off = 0;
    float* bnsum = ws + off; off += OUTC;
    float* bnsq  = ws + off; off += OUTC;
    float* ksuml = ws + off; off += (size_t)T_ * DK;
    float* ksumr = ws + off; off += (size_t)T_ * DK;
    float* zl    = ws + off; off += (size_t)T_ * INC;
    float* zr    = ws + off; off += (size_t)T_ * INC;
    float* scale = ws + off; off += OUTC;
    float* shift = ws + off; off += OUTC;

    u16* ub = (u16*)(ws + off);
    size_t uo = 0;
    u16* qb   = ub + uo; uo += (size_t)T_ * INC * DK;
    u16* klt  = ub + uo; uo += (size_t)T_ * DK * INC;
    u16* krt  = ub + uo; uo += (size_t)T_ * DK * INC;
    u16* kvlT = ub + uo; uo += (size_t)T_ * FD * DK;
    u16* kvrT = ub + uo; uo += (size_t)T_ * FD * DK;
    u16* newT = ub + uo; uo += (size_t)T_ * FD * INC;
    u16* xT   = ub + uo; uo += (size_t)B_ * FD * INC;
    u16* wqT  = ub + uo; uo += (size_t)DK * FD;
    u16* wklT = ub + uo; uo += (size_t)DK * FD;
    u16* wkrT = ub + uo; uo += (size_t)DK * FD;
    u16* upwT = ub + uo; uo += (size_t)FD * INC;
    u16* Wt   = ub + uo; uo += (size_t)9 * OUTC * 2 * INC;
    u16* P    = ub + uo; uo += (size_t)B_ * 66 * 66 * 512;

    // zero bnsum, bnsq, ksuml, ksumr (contiguous)
    hipMemsetAsync(bnsum, 0, (2 * OUTC + 2 * T_ * DK) * sizeof(float), stream);

    kborder<<<dim3(13, B_), dim3(256), 0, stream>>>(P);
    kprep_x<<<dim3(16, 8, B_), dim3(256), 0, stream>>>(x, xT);
    ktr_w<<<dim3(2, 16), dim3(256), 0, stream>>>(wq, wqT, FD, DK);
    ktr_w<<<dim3(2, 16), dim3(256), 0, stream>>>(wkl, wklT, FD, DK);
    ktr_w<<<dim3(2, 16), dim3(256), 0, stream>>>(wkr, wkrT, FD, DK);
    ktr_w<<<dim3(16, 8), dim3(256), 0, stream>>>(up_w, upwT, INC, FD);
    kw_tr<<<dim3((256 * 512 * 9 + 255) / 256), dim3(256), 0, stream>>>(c1_w, Wt);

    k1_proj<<<dim3(2, 4, 42), dim3(256), 0, stream>>>(x, wqT, wklT, wkrT, qb, klt, krt);
    k2b_ksum<<<dim3(T_, 8), dim3(128), 0, stream>>>(klt, krt, ksuml, ksumr);
    k2c_z<<<dim3(T_), dim3(512), 0, stream>>>(qb, ksuml, ksumr, zl, zr);
    k2_kv<<<dim3(2, 8, 28), dim3(256), 0, stream>>>(xT, klt, krt, kvlT, kvrT);
    k3_out<<<dim3(8, 8, T_), dim3(256), 0, stream>>>(xT, qb, kvlT, kvrT, zl, zr, newT);
    k4b_sfill<<<dim3(64, B_), dim3(256), 0, stream>>>(s_in, P);
    k4_up<<<dim3(16, 8, B_), dim3(256), 0, stream>>>(xT, newT, upwT, up_b, P);
    k5_mfma<<<dim3(16, 2, B_), dim3(256), 0, stream>>>(P, Wt, c1_b, y, bnsum, bnsq);
    k7_bnfin<<<dim3(1), dim3(OUTC), 0, stream>>>(bnsum, bnsq, bn_g, bn_b, scale, shift);
    k8_apply<<<dim3((B_ * OUTC * SP / 4) / 256), dim3(256), 0, stream>>>(y, scale, shift);
}